// Round 6
// baseline (351.783 us; speedup 1.0000x reference)
//
#include <hip/hip_runtime.h>
#include <stdint.h>

#define Bb 2
#define Tt 2048
#define Cc 1024
#define Hh 16
#define HD 64
#define C3 3072

typedef __bf16 bf16x8 __attribute__((ext_vector_type(8)));
typedef float  f32x4  __attribute__((ext_vector_type(4)));
typedef unsigned short u16;
typedef u16 u16x8 __attribute__((ext_vector_type(8)));
typedef u16 u16x4 __attribute__((ext_vector_type(4)));

#define SCALE2 0.18033688f  /* 1/sqrt(64) * log2(e) */

__device__ __forceinline__ u16 f2bf(float f) {
  union { float f; unsigned u; } v; v.f = f;
  return (u16)((v.u + 0x7fffu + ((v.u >> 16) & 1u)) >> 16);  // RNE
}
__device__ __forceinline__ u16 f2bf_fast(float f) {
  union { float f; unsigned u; } v; v.f = f;
  return (u16)((v.u + 0x8000u) >> 16);  // round-half-up, 2 instr
}
__device__ __forceinline__ float bf2f(u16 a) {
  union { unsigned u; float f; } v; v.u = ((unsigned)a) << 16; return v.f;
}

// async global->LDS, 16B per lane (GEMM staging only).
__device__ __forceinline__ void gl2lds16(const void* g, void* s) {
  __builtin_amdgcn_global_load_lds(
      (__attribute__((address_space(1))) void*)(g),
      (__attribute__((address_space(3))) void*)(s), 16, 0, 0);
}

// ---------------- fp32 -> bf16 elementwise ----------------
__global__ void cvt_x_kernel(const float* __restrict__ in, u16* __restrict__ out, int n4) {
  int i = blockIdx.x * blockDim.x + threadIdx.x;
  if (i < n4) {
    float4 v = ((const float4*)in)[i];
    u16x4 o = { f2bf(v.x), f2bf(v.y), f2bf(v.z), f2bf(v.w) };
    ((u16x4*)out)[i] = o;
  }
}

// ---------------- fp32 [R][C] -> bf16 [C][R] tiled transpose ----------------
__global__ void transpose_cvt(const float* __restrict__ in, u16* __restrict__ out,
                              int R, int C) {
  __shared__ u16 tile[64][65];
  int c0 = blockIdx.x * 64, r0 = blockIdx.y * 64;
  int x = threadIdx.x & 63, y = threadIdx.x >> 6;
  #pragma unroll
  for (int rr = y; rr < 64; rr += 4)
    tile[rr][x] = f2bf(in[(size_t)(r0 + rr) * C + c0 + x]);
  __syncthreads();
  #pragma unroll
  for (int rr = y; rr < 64; rr += 4)
    out[(size_t)(c0 + rr) * R + r0 + x] = tile[x][rr];
}

// ---------------- bf16 GEMM: C[M][N] = A[M][K] * Bt[N][K]^T + bias ----------------
template <int MODE>
__global__ __launch_bounds__(256)
void gemm_bt(const u16* __restrict__ A, const u16* __restrict__ Bt,
             const float* __restrict__ bias, void* __restrict__ Cout,
             u16* __restrict__ Vt, int M, int N, int K) {
  __shared__ u16 As[128 * 32];
  __shared__ u16 Bs[128 * 32];
  const int tid = threadIdx.x;
  const int ln  = tid & 63;
  const int w   = tid >> 6;
  const int wm  = w >> 1, wn = w & 1;
  const int l15 = ln & 15, lq = ln >> 4;
  const int m0 = blockIdx.y * 128, n0 = blockIdx.x * 128;

  f32x4 acc[4][4];
  #pragma unroll
  for (int i = 0; i < 4; ++i)
    #pragma unroll
    for (int j = 0; j < 4; ++j)
      acc[i][j] = (f32x4){0.f, 0.f, 0.f, 0.f};

  for (int k0 = 0; k0 < K; k0 += 32) {
    #pragma unroll
    for (int i = 0; i < 2; ++i) {
      int chunk = i * 256 + tid;      // 0..511, 8 bf16 each
      int row = chunk >> 2;           // tile row 0..127
      int cg  = chunk & 3;            // k-group
      gl2lds16(A  + (size_t)(m0 + row) * K + k0 + cg * 8,
               (char*)As + (size_t)(i * 256 + w * 64) * 16);
      gl2lds16(Bt + (size_t)(n0 + row) * K + k0 + cg * 8,
               (char*)Bs + (size_t)(i * 256 + w * 64) * 16);
    }
    __syncthreads();
    bf16x8 af[4], bfr[4];
    #pragma unroll
    for (int i = 0; i < 4; ++i) {
      af[i]  = *(const bf16x8*)&As[(wm * 64 + i * 16 + l15) * 32 + lq * 8];
      bfr[i] = *(const bf16x8*)&Bs[(wn * 64 + i * 16 + l15) * 32 + lq * 8];
    }
    #pragma unroll
    for (int i = 0; i < 4; ++i)
      #pragma unroll
      for (int j = 0; j < 4; ++j)
        acc[i][j] = __builtin_amdgcn_mfma_f32_16x16x32_bf16(af[i], bfr[j], acc[i][j], 0, 0, 0);
    __syncthreads();
  }

  if (MODE == 1 && n0 >= 2048) {
    #pragma unroll
    for (int i = 0; i < 4; ++i) {
      int rowb = m0 + wm * 64 + i * 16 + lq * 4;   // 4 consecutive t
      int b_ = rowb >> 11, t0 = rowb & 2047;
      #pragma unroll
      for (int j = 0; j < 4; ++j) {
        int col = n0 + wn * 64 + j * 16 + l15;
        int hd = col - 2048;
        float bsv = bias[col];
        u16x4 pk;
        #pragma unroll
        for (int r = 0; r < 4; ++r) pk[r] = f2bf(acc[i][j][r] + bsv);
        *(u16x4*)&Vt[(size_t)(b_ * 1024 + hd) * Tt + t0] = pk;
      }
    }
  } else {
    const int ldc = (MODE == 1) ? 2048 : N;
    #pragma unroll
    for (int i = 0; i < 4; ++i) {
      int row = m0 + wm * 64 + i * 16 + lq * 4;
      #pragma unroll
      for (int j = 0; j < 4; ++j) {
        int col = n0 + wn * 64 + j * 16 + l15;
        float bsv = bias[col];
        #pragma unroll
        for (int r = 0; r < 4; ++r) {
          float v = acc[i][j][r] + bsv;
          if (MODE == 1) ((u16*)Cout)[(size_t)(row + r) * ldc + col] = f2bf(v);
          else           ((float*)Cout)[(size_t)(row + r) * ldc + col] = v;
        }
      }
    }
  }
}

// ============ fused causal flash attention — 16 q-rows/wave, split-kv ============
// S^T = K*Q^T: C-layout (col=q, row=kv) repacks in-register into the PV
// A-fragment under the joint kv permutation; V fragments load directly from
// global V^T. Block = 128 thr = 2 waves over the SAME 16 q rows; wave 0 takes
// even kv tiles, wave 1 odd; combine via 4.5 KB LDS + one barrier.
// Peak live state ~80 VGPR (q8 + o16 + ml2 + kf16 + t16 + addr) -> no spill.

__device__ __forceinline__ bf16x8 ldb8(const u16* p) {
  return __builtin_bit_cast(bf16x8, *(const u16x8*)p);
}
__device__ __forceinline__ bf16x8 vfrag(const u16* vrow, int c0) {
  u16x4 a = *(const u16x4*)(vrow + c0);
  u16x4 b = *(const u16x4*)(vrow + c0 + 16);
  u16x8 u = { a[0], a[1], a[2], a[3], b[0], b[1], b[2], b[3] };
  return __builtin_bit_cast(bf16x8, u);
}
__device__ __forceinline__ bf16x8 packp(const f32x4& a, const f32x4& b) {
  u16x8 u = { f2bf_fast(a[0]), f2bf_fast(a[1]), f2bf_fast(a[2]), f2bf_fast(a[3]),
              f2bf_fast(b[0]), f2bf_fast(b[1]), f2bf_fast(b[2]), f2bf_fast(b[3]) };
  return __builtin_bit_cast(bf16x8, u);
}
__device__ __forceinline__ bf16x8 qscale(const u16* p) {
  u16x8 q = *(const u16x8*)p;
  u16x8 s;
  #pragma unroll
  for (int j = 0; j < 8; ++j) s[j] = f2bf(bf2f(q[j]) * SCALE2);
  return __builtin_bit_cast(bf16x8, s);
}

__global__ __launch_bounds__(128, 4)
void attn_fused(const u16* __restrict__ qk, const u16* __restrict__ vt,
                u16* __restrict__ y) {
  __shared__ float ocomb[16 * 68];   // wave-1 partial O, padded stride 68
  __shared__ float mlcomb[32];       // m[0..15], l[16..31]
  const int tid = threadIdx.x;
  const int ln = tid & 63, w = tid >> 6;
  const int l15 = ln & 15, lq = ln >> 4;
  const int bx = blockIdx.x;
  const int bh = bx & 31;            // (b,h)
  const int h  = bh & 15, b = bh >> 4;
  const int qt = 127 - (bx >> 5);    // heavy tiles dispatched first
  const int q0 = qt * 16;

  const u16* qbase = qk + (size_t)(b * Tt) * 2048 + h * HD;
  const u16* kbase = qk + (size_t)(b * Tt) * 2048 + 1024 + h * HD;
  const u16* vbase = vt + (size_t)(b * 1024 + h * HD) * Tt;

  // Q B-fragments (n=q, k=d), prescaled by 1/sqrt(d)*log2e
  const u16* qrA = qbase + (size_t)(q0 + l15) * 2048;
  bf16x8 qA0 = qscale(qrA + lq * 8), qA1 = qscale(qrA + 32 + lq * 8);

  f32x4 oA[4];
  #pragma unroll
  for (int j = 0; j < 4; ++j) oA[j] = (f32x4){0,0,0,0};
  float mA = -__builtin_inff();
  float lA = 0.f;
  const int qg = q0 + l15;           // this lane's q column (for mask + softmax)

  const int nkv = (qt >> 2) + 1;

  for (int it = w; it < nkv; it += 2) {
    const int kk = it * 64;
    const bool lastI = (it == nkv - 1);

    // S^T = K * Q^T, K in d-halves (16 regs live)
    f32x4 t[4];
    #pragma unroll
    for (int i = 0; i < 4; ++i) t[i] = (f32x4){0,0,0,0};
    {
      bf16x8 kf[4];
      #pragma unroll
      for (int i = 0; i < 4; ++i)
        kf[i] = ldb8(kbase + (size_t)(kk + i * 16 + l15) * 2048 + lq * 8);
      #pragma unroll
      for (int i = 0; i < 4; ++i)
        t[i] = __builtin_amdgcn_mfma_f32_16x16x32_bf16(kf[i], qA0, t[i], 0, 0, 0);
      #pragma unroll
      for (int i = 0; i < 4; ++i)
        kf[i] = ldb8(kbase + (size_t)(kk + i * 16 + l15) * 2048 + 32 + lq * 8);
      #pragma unroll
      for (int i = 0; i < 4; ++i)
        t[i] = __builtin_amdgcn_mfma_f32_16x16x32_bf16(kf[i], qA1, t[i], 0, 0, 0);
    }

    // V first kv-half: issue early, consumed after softmax (reg headroom ok now)
    bf16x8 vf[4];
    #pragma unroll
    for (int jd = 0; jd < 4; ++jd)
      vf[jd] = vfrag(vbase + (size_t)(jd * 16 + l15) * Tt, kk + lq * 4);

    // online softmax (values in log2 domain)
    if (lastI) {
      #pragma unroll
      for (int i = 0; i < 4; ++i)
        #pragma unroll
        for (int r = 0; r < 4; ++r) {
          int kv = kk + i * 16 + lq * 4 + r;
          if (kv > qg) t[i][r] = -__builtin_inff();
        }
    }
    float mx = t[0][0];
    #pragma unroll
    for (int i = 0; i < 4; ++i)
      #pragma unroll
      for (int r = 0; r < 4; ++r) mx = fmaxf(mx, t[i][r]);
    mx = fmaxf(mx, __shfl_xor(mx, 16));
    mx = fmaxf(mx, __shfl_xor(mx, 32));
    float mn = fmaxf(mA, mx);
    float al = __builtin_amdgcn_exp2f(mA - mn);
    float ps = 0.f;
    #pragma unroll
    for (int i = 0; i < 4; ++i)
      #pragma unroll
      for (int r = 0; r < 4; ++r) {
        float p = __builtin_amdgcn_exp2f(t[i][r] - mn);
        t[i][r] = p;
        ps += p;
      }
    ps += __shfl_xor(ps, 16);
    ps += __shfl_xor(ps, 32);
    lA = lA * al + ps;
    mA = mn;
    #pragma unroll
    for (int r = 0; r < 4; ++r) {
      float alr = __shfl(al, (ln & 48) + lq * 4 + r, 64);
      #pragma unroll
      for (int jd = 0; jd < 4; ++jd) oA[jd][r] *= alr;
    }

    bf16x8 pA0 = packp(t[0], t[1]), pA1 = packp(t[2], t[3]);

    #pragma unroll
    for (int jd = 0; jd < 4; ++jd)
      oA[jd] = __builtin_amdgcn_mfma_f32_16x16x32_bf16(pA0, vf[jd], oA[jd], 0, 0, 0);
    #pragma unroll
    for (int jd = 0; jd < 4; ++jd)
      vf[jd] = vfrag(vbase + (size_t)(jd * 16 + l15) * Tt, kk + 32 + lq * 4);
    #pragma unroll
    for (int jd = 0; jd < 4; ++jd)
      oA[jd] = __builtin_amdgcn_mfma_f32_16x16x32_bf16(pA1, vf[jd], oA[jd], 0, 0, 0);
  }

  // ---- combine the two waves' partial (m, l, o) ----
  if (w == 1) {
    #pragma unroll
    for (int r = 0; r < 4; ++r)
      #pragma unroll
      for (int jd = 0; jd < 4; ++jd)
        ocomb[(lq * 4 + r) * 68 + jd * 16 + l15] = oA[jd][r];
    if (lq == 0) {
      mlcomb[l15]      = mA;
      mlcomb[16 + l15] = lA;
    }
  }
  __syncthreads();
  if (w == 0) {
    #pragma unroll
    for (int r = 0; r < 4; ++r) {
      int rA = lq * 4 + r;
      float m1 = mlcomb[rA], l1 = mlcomb[16 + rA];
      float m0 = __shfl(mA, (ln & 48) + rA, 64);
      float l0 = __shfl(lA, (ln & 48) + rA, 64);
      float ms = fmaxf(m0, m1);
      float a0 = __builtin_amdgcn_exp2f(m0 - ms);
      float a1 = __builtin_amdgcn_exp2f(m1 - ms);
      float inv = 1.f / (l0 * a0 + l1 * a1);
      int row = q0 + rA;
      #pragma unroll
      for (int jd = 0; jd < 4; ++jd) {
        float v = (oA[jd][r] * a0 + ocomb[rA * 68 + jd * 16 + l15] * a1) * inv;
        y[(size_t)(b * Tt + row) * Cc + h * HD + jd * 16 + l15] = f2bf(v);
      }
    }
  }
}

extern "C" void kernel_launch(void* const* d_in, const int* in_sizes, int n_in,
                              void* d_out, int out_size, void* d_ws, size_t ws_size,
                              hipStream_t stream) {
  const float* x      = (const float*)d_in[0];
  const float* w_attn = (const float*)d_in[1];
  const float* b_attn = (const float*)d_in[2];
  const float* w_proj = (const float*)d_in[3];
  const float* b_proj = (const float*)d_in[4];
  float* out = (float*)d_out;

  char* ws = (char*)d_ws;
  u16* xb  = (u16*)(ws + 0);          // 4096x1024 bf16   (8 MB)
  u16* wat = (u16*)(ws + 8388608);    // 3072x1024 bf16   (6 MB)   w_attn^T
  u16* wpt = (u16*)(ws + 14680064);   // 1024x1024 bf16   (2 MB)   w_proj^T
  u16* qkb = (u16*)(ws + 16777216);   // 4096x2048 bf16   (16 MB)  Q,K
  u16* vtb = (u16*)(ws + 33554432);   // 2048x2048 bf16   (8 MB)   V^T per (b,h)
  u16* yb  = (u16*)(ws + 41943040);   // 4096x1024 bf16   (8 MB)

  cvt_x_kernel<<<4096, 256, 0, stream>>>(x, xb, 1048576);
  transpose_cvt<<<dim3(48, 16), 256, 0, stream>>>(w_attn, wat, 1024, 3072);
  transpose_cvt<<<dim3(16, 16), 256, 0, stream>>>(w_proj, wpt, 1024, 1024);
  gemm_bt<1><<<dim3(24, 32), 256, 0, stream>>>(xb, wat, b_attn, (void*)qkb, vtb, 4096, 3072, 1024);
  attn_fused<<<4096, 128, 0, stream>>>(qkb, vtb, yb);
  gemm_bt<0><<<dim3(8, 32), 256, 0, stream>>>(yb, wpt, b_proj, (void*)out, nullptr, 4096, 1024, 1024);
}

// Round 7
// 215.238 us; speedup vs baseline: 1.6344x; 1.6344x over previous
//
#include <hip/hip_runtime.h>
#include <stdint.h>

#define Bb 2
#define Tt 2048
#define Cc 1024
#define Hh 16
#define HD 64
#define C3 3072

typedef __bf16 bf16x8 __attribute__((ext_vector_type(8)));
typedef float  f32x4  __attribute__((ext_vector_type(4)));
typedef unsigned short u16;
typedef u16 u16x8 __attribute__((ext_vector_type(8)));
typedef u16 u16x4 __attribute__((ext_vector_type(4)));

#define SCALE2 0.18033688f  /* 1/sqrt(64) * log2(e) */

__device__ __forceinline__ u16 f2bf(float f) {
  union { float f; unsigned u; } v; v.f = f;
  return (u16)((v.u + 0x7fffu + ((v.u >> 16) & 1u)) >> 16);  // RNE
}
__device__ __forceinline__ u16 f2bf_fast(float f) {
  union { float f; unsigned u; } v; v.f = f;
  return (u16)((v.u + 0x8000u) >> 16);  // round-half-up, 2 instr
}
__device__ __forceinline__ float bf2f(u16 a) {
  union { unsigned u; float f; } v; v.u = ((unsigned)a) << 16; return v.f;
}

// async global->LDS, 16B per lane. LDS dest = wave-uniform base + lane*16.
__device__ __forceinline__ void gl2lds16(const void* g, void* s) {
  __builtin_amdgcn_global_load_lds(
      (__attribute__((address_space(1))) void*)(g),
      (__attribute__((address_space(3))) void*)(s), 16, 0, 0);
}

// ---------------- fp32 -> bf16 elementwise ----------------
__global__ void cvt_x_kernel(const float* __restrict__ in, u16* __restrict__ out, int n4) {
  int i = blockIdx.x * blockDim.x + threadIdx.x;
  if (i < n4) {
    float4 v = ((const float4*)in)[i];
    u16x4 o = { f2bf(v.x), f2bf(v.y), f2bf(v.z), f2bf(v.w) };
    ((u16x4*)out)[i] = o;
  }
}

// ---------------- fp32 [R][C] -> bf16 [C][R] tiled transpose ----------------
__global__ void transpose_cvt(const float* __restrict__ in, u16* __restrict__ out,
                              int R, int C) {
  __shared__ u16 tile[64][65];
  int c0 = blockIdx.x * 64, r0 = blockIdx.y * 64;
  int x = threadIdx.x & 63, y = threadIdx.x >> 6;
  #pragma unroll
  for (int rr = y; rr < 64; rr += 4)
    tile[rr][x] = f2bf(in[(size_t)(r0 + rr) * C + c0 + x]);
  __syncthreads();
  #pragma unroll
  for (int rr = y; rr < 64; rr += 4)
    out[(size_t)(c0 + rr) * R + r0 + x] = tile[x][rr];
}

// ---------------- bf16 GEMM: C[M][N] = A[M][K] * Bt[N][K]^T + bias ----------------
template <int MODE>
__global__ __launch_bounds__(256)
void gemm_bt(const u16* __restrict__ A, const u16* __restrict__ Bt,
             const float* __restrict__ bias, void* __restrict__ Cout,
             u16* __restrict__ Vt, int M, int N, int K) {
  __shared__ u16 As[128 * 32];
  __shared__ u16 Bs[128 * 32];
  const int tid = threadIdx.x;
  const int ln  = tid & 63;
  const int w   = tid >> 6;
  const int wm  = w >> 1, wn = w & 1;
  const int l15 = ln & 15, lq = ln >> 4;
  const int m0 = blockIdx.y * 128, n0 = blockIdx.x * 128;

  f32x4 acc[4][4];
  #pragma unroll
  for (int i = 0; i < 4; ++i)
    #pragma unroll
    for (int j = 0; j < 4; ++j)
      acc[i][j] = (f32x4){0.f, 0.f, 0.f, 0.f};

  for (int k0 = 0; k0 < K; k0 += 32) {
    #pragma unroll
    for (int i = 0; i < 2; ++i) {
      int chunk = i * 256 + tid;      // 0..511, 8 bf16 each
      int row = chunk >> 2;           // tile row 0..127
      int cg  = chunk & 3;            // k-group
      gl2lds16(A  + (size_t)(m0 + row) * K + k0 + cg * 8,
               (char*)As + (size_t)(i * 256 + w * 64) * 16);
      gl2lds16(Bt + (size_t)(n0 + row) * K + k0 + cg * 8,
               (char*)Bs + (size_t)(i * 256 + w * 64) * 16);
    }
    __syncthreads();
    bf16x8 af[4], bfr[4];
    #pragma unroll
    for (int i = 0; i < 4; ++i) {
      af[i]  = *(const bf16x8*)&As[(wm * 64 + i * 16 + l15) * 32 + lq * 8];
      bfr[i] = *(const bf16x8*)&Bs[(wn * 64 + i * 16 + l15) * 32 + lq * 8];
    }
    #pragma unroll
    for (int i = 0; i < 4; ++i)
      #pragma unroll
      for (int j = 0; j < 4; ++j)
        acc[i][j] = __builtin_amdgcn_mfma_f32_16x16x32_bf16(af[i], bfr[j], acc[i][j], 0, 0, 0);
    __syncthreads();
  }

  if (MODE == 1 && n0 >= 2048) {
    #pragma unroll
    for (int i = 0; i < 4; ++i) {
      int rowb = m0 + wm * 64 + i * 16 + lq * 4;   // 4 consecutive t
      int b_ = rowb >> 11, t0 = rowb & 2047;
      #pragma unroll
      for (int j = 0; j < 4; ++j) {
        int col = n0 + wn * 64 + j * 16 + l15;
        int hd = col - 2048;
        float bsv = bias[col];
        u16x4 pk;
        #pragma unroll
        for (int r = 0; r < 4; ++r) pk[r] = f2bf(acc[i][j][r] + bsv);
        *(u16x4*)&Vt[(size_t)(b_ * 1024 + hd) * Tt + t0] = pk;
      }
    }
  } else {
    const int ldc = (MODE == 1) ? 2048 : N;
    #pragma unroll
    for (int i = 0; i < 4; ++i) {
      int row = m0 + wm * 64 + i * 16 + lq * 4;
      #pragma unroll
      for (int j = 0; j < 4; ++j) {
        int col = n0 + wn * 64 + j * 16 + l15;
        float bsv = bias[col];
        #pragma unroll
        for (int r = 0; r < 4; ++r) {
          float v = acc[i][j][r] + bsv;
          if (MODE == 1) ((u16*)Cout)[(size_t)(row + r) * ldc + col] = f2bf(v);
          else           ((float*)Cout)[(size_t)(row + r) * ldc + col] = v;
        }
      }
    }
  }
}

// ============ fused causal flash attention — LDS-staged, swizzled, O^T ============
// Block = 256 thr = 4 waves, q-tile 64 (wave w: rows q0+w*16..+15), kv-tile 64.
// K and V^T staged global->LDS (coalesced gl2lds16, shared by all 4 waves) with
// XOR swizzle: slot s holds 16B chunk ((s&7)^((s>>3)&7)) of row s>>3, so
// fragment ds_reads are conflict-free (each lane-octet covers all 32 banks).
// S^T = K*Q^T (A=K from LDS, B=Q regs). O^T = V^T*P: the same packp() vector
// is the PV B-fragment; V^T A-fragments come from LDS under the joint kv
// permutation. q-index lives in lane l15 for S^T, softmax state AND O^T ->
// zero cross-lane shuffles for alpha/epilogue.

__device__ __forceinline__ bf16x8 ldb8(const u16* p) {
  return __builtin_bit_cast(bf16x8, *(const u16x8*)p);
}
__device__ __forceinline__ bf16x8 packp(const f32x4& a, const f32x4& b) {
  u16x8 u = { f2bf_fast(a[0]), f2bf_fast(a[1]), f2bf_fast(a[2]), f2bf_fast(a[3]),
              f2bf_fast(b[0]), f2bf_fast(b[1]), f2bf_fast(b[2]), f2bf_fast(b[3]) };
  return __builtin_bit_cast(bf16x8, u);
}
__device__ __forceinline__ bf16x8 qscale(const u16* p) {
  u16x8 q = *(const u16x8*)p;
  u16x8 s;
  #pragma unroll
  for (int j = 0; j < 8; ++j) s[j] = f2bf(bf2f(q[j]) * SCALE2);
  return __builtin_bit_cast(bf16x8, s);
}

__global__ __launch_bounds__(256, 4)
void attn_fused(const u16* __restrict__ qk, const u16* __restrict__ vt,
                u16* __restrict__ y) {
  __shared__ u16 Ks[64 * 64];    // swizzled [kv-row][d]
  __shared__ u16 Vts[64 * 64];   // swizzled [d-row][kv]
  const int tid = threadIdx.x;
  const int ln = tid & 63, w = tid >> 6;
  const int l15 = ln & 15, lq = ln >> 4;
  const int swz = l15 & 7;
  const int bx = blockIdx.x;
  const int bh = bx & 31;
  const int h  = bh & 15, b = bh >> 4;
  // balanced heavy/light rounds: each CU's 4 resident blocks sum to ~62 iters
  const int rr_ = bx >> 8, g = (bx >> 5) & 7;
  const int qt = (rr_ == 0) ? 31 - g : (rr_ == 1) ? 16 + g : (rr_ == 2) ? 15 - g : g;
  const int q0 = qt * 64;
  const int q0w = q0 + w * 16;

  const u16* qbase = qk + (size_t)(b * Tt) * 2048 + h * HD;
  const u16* kbase = qk + (size_t)(b * Tt) * 2048 + 1024 + h * HD;
  const u16* vbase = vt + (size_t)(b * 1024 + h * HD) * Tt;

  // staging: thread handles slots s0=tid, s1=256+tid; row=s>>3, swizzled chunk
  const int s0 = tid, s1 = 256 + tid;
  const int koff0 = (s0 >> 3) * 2048 + (((s0 & 7) ^ ((s0 >> 3) & 7)) * 8);
  const int koff1 = (s1 >> 3) * 2048 + (((s1 & 7) ^ ((s1 >> 3) & 7)) * 8);
  char* kd0 = (char*)Ks  + w * 1024;
  char* kd1 = (char*)Ks  + 4096 + w * 1024;
  char* vd0 = (char*)Vts + w * 1024;
  char* vd1 = (char*)Vts + 4096 + w * 1024;

  // Q B-fragments (n=q=l15, k=d), prescaled by 1/sqrt(d)*log2e
  const u16* qrA = qbase + (size_t)(q0w + l15) * 2048;
  bf16x8 qA0 = qscale(qrA + lq * 8), qA1 = qscale(qrA + 32 + lq * 8);

  f32x4 o[4];
  #pragma unroll
  for (int j = 0; j < 4; ++j) o[j] = (f32x4){0,0,0,0};
  float m = -__builtin_inff(), l = 0.f;
  const int qg = q0w + l15;

  const int nkv = qt + 1;
  for (int it = 0; it < nkv; ++it) {
    const int kk = it * 64;
    __syncthreads();   // previous iteration's LDS readers done
    {
      const u16* ksrc = kbase + (size_t)kk * 2048;
      const u16* vsrc = vbase + kk;
      gl2lds16(ksrc + koff0, kd0);
      gl2lds16(ksrc + koff1, kd1);
      gl2lds16(vsrc + koff0, vd0);
      gl2lds16(vsrc + koff1, vd1);
    }
    __syncthreads();   // staging complete (drains vmcnt)

    // S^T = K * Q^T
    f32x4 t[4];
    #pragma unroll
    for (int i = 0; i < 4; ++i) t[i] = (f32x4){0,0,0,0};
    #pragma unroll
    for (int i = 0; i < 4; ++i) {
      bf16x8 kf0 = ldb8(&Ks[(i * 16 + l15) * 64 + ((lq    ) ^ swz) * 8]);
      bf16x8 kf1 = ldb8(&Ks[(i * 16 + l15) * 64 + ((lq + 4) ^ swz) * 8]);
      t[i] = __builtin_amdgcn_mfma_f32_16x16x32_bf16(kf0, qA0, t[i], 0, 0, 0);
      t[i] = __builtin_amdgcn_mfma_f32_16x16x32_bf16(kf1, qA1, t[i], 0, 0, 0);
    }

    // online softmax over kv (log2 domain); state per q = per lane (l15)
    const bool lastI = (it == nkv - 1);
    if (lastI) {
      #pragma unroll
      for (int i = 0; i < 4; ++i)
        #pragma unroll
        for (int r = 0; r < 4; ++r) {
          int kv = kk + i * 16 + lq * 4 + r;
          if (kv > qg) t[i][r] = -__builtin_inff();
        }
    }
    float mx = t[0][0];
    #pragma unroll
    for (int i = 0; i < 4; ++i)
      #pragma unroll
      for (int r = 0; r < 4; ++r) mx = fmaxf(mx, t[i][r]);
    mx = fmaxf(mx, __shfl_xor(mx, 16));
    mx = fmaxf(mx, __shfl_xor(mx, 32));
    float mn = fmaxf(m, mx);
    float al = __builtin_amdgcn_exp2f(m - mn);
    float ps = 0.f;
    #pragma unroll
    for (int i = 0; i < 4; ++i)
      #pragma unroll
      for (int r = 0; r < 4; ++r) {
        float p = __builtin_amdgcn_exp2f(t[i][r] - mn);
        t[i][r] = p;
        ps += p;
      }
    ps += __shfl_xor(ps, 16);
    ps += __shfl_xor(ps, 32);
    l = l * al + ps;
    m = mn;
    #pragma unroll
    for (int jd = 0; jd < 4; ++jd)
      #pragma unroll
      for (int r = 0; r < 4; ++r) o[jd][r] *= al;   // per-lane alpha, no shuffle

    // O^T += V^T * P  (A = V^T frags from LDS, B = packp vectors)
    bf16x8 p0 = packp(t[0], t[1]), p1 = packp(t[2], t[3]);
    #pragma unroll
    for (int mf = 0; mf < 2; ++mf) {
      bf16x8 pb = mf ? p1 : p0;
      #pragma unroll
      for (int jd = 0; jd < 4; ++jd) {
        int d = jd * 16 + l15;
        int plo = ((mf * 4     + (lq >> 1)) ^ swz);
        int phi = ((mf * 4 + 2 + (lq >> 1)) ^ swz);
        u16x4 a = *(const u16x4*)&Vts[d * 64 + plo * 8 + (lq & 1) * 4];
        u16x4 c = *(const u16x4*)&Vts[d * 64 + phi * 8 + (lq & 1) * 4];
        u16x8 u = { a[0], a[1], a[2], a[3], c[0], c[1], c[2], c[3] };
        o[jd] = __builtin_amdgcn_mfma_f32_16x16x32_bf16(
                    __builtin_bit_cast(bf16x8, u), pb, o[jd], 0, 0, 0);
      }
    }
  }

  // epilogue: per-lane normalize, store O^T[d][q] -> y[q][d] as u16x4 runs
  float inv = 1.f / l;
  const size_t ybase = (size_t)(b * Tt + q0w + l15) * Cc + h * HD;
  #pragma unroll
  for (int jd = 0; jd < 4; ++jd) {
    u16x4 pk;
    #pragma unroll
    for (int r = 0; r < 4; ++r) pk[r] = f2bf(o[jd][r] * inv);
    *(u16x4*)&y[ybase + jd * 16 + lq * 4] = pk;
  }
}

extern "C" void kernel_launch(void* const* d_in, const int* in_sizes, int n_in,
                              void* d_out, int out_size, void* d_ws, size_t ws_size,
                              hipStream_t stream) {
  const float* x      = (const float*)d_in[0];
  const float* w_attn = (const float*)d_in[1];
  const float* b_attn = (const float*)d_in[2];
  const float* w_proj = (const float*)d_in[3];
  const float* b_proj = (const float*)d_in[4];
  float* out = (float*)d_out;

  char* ws = (char*)d_ws;
  u16* xb  = (u16*)(ws + 0);          // 4096x1024 bf16   (8 MB)
  u16* wat = (u16*)(ws + 8388608);    // 3072x1024 bf16   (6 MB)   w_attn^T
  u16* wpt = (u16*)(ws + 14680064);   // 1024x1024 bf16   (2 MB)   w_proj^T
  u16* qkb = (u16*)(ws + 16777216);   // 4096x2048 bf16   (16 MB)  Q,K
  u16* vtb = (u16*)(ws + 33554432);   // 2048x2048 bf16   (8 MB)   V^T per (b,h)
  u16* yb  = (u16*)(ws + 41943040);   // 4096x1024 bf16   (8 MB)

  cvt_x_kernel<<<4096, 256, 0, stream>>>(x, xb, 1048576);
  transpose_cvt<<<dim3(48, 16), 256, 0, stream>>>(w_attn, wat, 1024, 3072);
  transpose_cvt<<<dim3(16, 16), 256, 0, stream>>>(w_proj, wpt, 1024, 1024);
  gemm_bt<1><<<dim3(24, 32), 256, 0, stream>>>(xb, wat, b_attn, (void*)qkb, vtb, 4096, 3072, 1024);
  attn_fused<<<1024, 256, 0, stream>>>(qkb, vtb, yb);
  gemm_bt<0><<<dim3(8, 32), 256, 0, stream>>>(yb, wpt, b_proj, (void*)out, nullptr, 4096, 1024, 1024);
}

// Round 8
// 196.861 us; speedup vs baseline: 1.7870x; 1.0934x over previous
//
#include <hip/hip_runtime.h>
#include <stdint.h>

#define Bb 2
#define Tt 2048
#define Cc 1024
#define Hh 16
#define HD 64
#define C3 3072

typedef __bf16 bf16x8 __attribute__((ext_vector_type(8)));
typedef float  f32x4  __attribute__((ext_vector_type(4)));
typedef unsigned short u16;
typedef u16 u16x8 __attribute__((ext_vector_type(8)));
typedef u16 u16x4 __attribute__((ext_vector_type(4)));

#define SCALE2 0.18033688f  /* 1/sqrt(64) * log2(e) */

__device__ __forceinline__ u16 f2bf(float f) {
  union { float f; unsigned u; } v; v.f = f;
  return (u16)((v.u + 0x7fffu + ((v.u >> 16) & 1u)) >> 16);  // RNE
}
__device__ __forceinline__ u16 f2bf_fast(float f) {
  union { float f; unsigned u; } v; v.f = f;
  return (u16)((v.u + 0x8000u) >> 16);  // round-half-up, 2 instr
}
__device__ __forceinline__ float bf2f(u16 a) {
  union { unsigned u; float f; } v; v.u = ((unsigned)a) << 16; return v.f;
}

// async global->LDS, 16B per lane. LDS dest = wave-uniform base + lane*16.
__device__ __forceinline__ void gl2lds16(const void* g, void* s) {
  __builtin_amdgcn_global_load_lds(
      (__attribute__((address_space(1))) void*)(g),
      (__attribute__((address_space(3))) void*)(s), 16, 0, 0);
}

__device__ __forceinline__ bf16x8 ldb8(const u16* p) {
  return __builtin_bit_cast(bf16x8, *(const u16x8*)p);
}

// ---------------- fp32 -> bf16 elementwise ----------------
__global__ void cvt_x_kernel(const float* __restrict__ in, u16* __restrict__ out, int n4) {
  int i = blockIdx.x * blockDim.x + threadIdx.x;
  if (i < n4) {
    float4 v = ((const float4*)in)[i];
    u16x4 o = { f2bf(v.x), f2bf(v.y), f2bf(v.z), f2bf(v.w) };
    ((u16x4*)out)[i] = o;
  }
}

// ---------------- fp32 [R][C] -> bf16 [C][R] tiled transpose ----------------
__global__ void transpose_cvt(const float* __restrict__ in, u16* __restrict__ out,
                              int R, int C) {
  __shared__ u16 tile[64][65];
  int c0 = blockIdx.x * 64, r0 = blockIdx.y * 64;
  int x = threadIdx.x & 63, y = threadIdx.x >> 6;
  #pragma unroll
  for (int rr = y; rr < 64; rr += 4)
    tile[rr][x] = f2bf(in[(size_t)(r0 + rr) * C + c0 + x]);
  __syncthreads();
  #pragma unroll
  for (int rr = y; rr < 64; rr += 4)
    out[(size_t)(c0 + rr) * R + r0 + x] = tile[x][rr];
}

// ---------------- bf16 GEMM: C[M][N] = A[M][K] * Bt[N][K]^T + bias ----------------
// 128xBN block tile, BK=64, 4 waves (2x2). XOR-swizzled LDS (chunk ^= row&7):
// staging source offset carries the swizzle (free), fragment ds_read_b128s hit
// 8 distinct bank-quads per 8-lane phase -> conflict-free.
// MODE 0: fp32 out, ldc=N.   MODE 1 (BN=128): bf16 out ldc=2048 for Q,K;
//         V cols (>=2048) written transposed into Vt[b][h][d][t].
template <int MODE, int BN>
__global__ __launch_bounds__(256)
void gemm_bt(const u16* __restrict__ A, const u16* __restrict__ Bt,
             const float* __restrict__ bias, void* __restrict__ Cout,
             u16* __restrict__ Vt, int M, int N, int K) {
  __shared__ u16 As[128 * 64];
  __shared__ u16 Bs[BN * 64];
  constexpr int JT = BN / 32;          // j-tiles per wave
  const int tid = threadIdx.x;
  const int ln  = tid & 63;
  const int w   = tid >> 6;
  const int wm  = w >> 1, wn = w & 1;
  const int l15 = ln & 15, lq = ln >> 4;
  const int swz = l15 & 7;
  const int m0 = blockIdx.y * 128, n0 = blockIdx.x * BN;

  f32x4 acc[4][JT];
  #pragma unroll
  for (int i = 0; i < 4; ++i)
    #pragma unroll
    for (int j = 0; j < JT; ++j)
      acc[i][j] = (f32x4){0.f, 0.f, 0.f, 0.f};

  for (int k0 = 0; k0 < K; k0 += 64) {
    #pragma unroll
    for (int i = 0; i < 4; ++i) {       // A: 128 rows x 8 chunks = 1024 slots
      int s = i * 256 + tid;
      int row = s >> 3, cg = s & 7;
      gl2lds16(A + (size_t)(m0 + row) * K + k0 + ((cg ^ (row & 7)) * 8),
               (char*)As + (size_t)(i * 256 + w * 64) * 16);
    }
    #pragma unroll
    for (int i = 0; i < BN / 32; ++i) { // B: BN rows x 8 chunks
      int s = i * 256 + tid;
      int row = s >> 3, cg = s & 7;
      gl2lds16(Bt + (size_t)(n0 + row) * K + k0 + ((cg ^ (row & 7)) * 8),
               (char*)Bs + (size_t)(i * 256 + w * 64) * 16);
    }
    __syncthreads();
    #pragma unroll
    for (int ho = 0; ho < 2; ++ho) {    // two K=32 halves per staging phase
      bf16x8 af[4], bfr[JT];
      #pragma unroll
      for (int i = 0; i < 4; ++i)
        af[i] = ldb8(&As[(wm * 64 + i * 16 + l15) * 64 + ((ho * 4 + lq) ^ swz) * 8]);
      #pragma unroll
      for (int j = 0; j < JT; ++j)
        bfr[j] = ldb8(&Bs[(wn * (BN / 2) + j * 16 + l15) * 64 + ((ho * 4 + lq) ^ swz) * 8]);
      #pragma unroll
      for (int i = 0; i < 4; ++i)
        #pragma unroll
        for (int j = 0; j < JT; ++j)
          acc[i][j] = __builtin_amdgcn_mfma_f32_16x16x32_bf16(af[i], bfr[j], acc[i][j], 0, 0, 0);
    }
    __syncthreads();
  }

  if (MODE == 1 && n0 >= 2048) {
    // V block: write transposed into Vt[(b*16+h)*64+d][t] = Vt[b*1024+hd][t]
    #pragma unroll
    for (int i = 0; i < 4; ++i) {
      int rowb = m0 + wm * 64 + i * 16 + lq * 4;   // 4 consecutive t
      int b_ = rowb >> 11, t0 = rowb & 2047;
      #pragma unroll
      for (int j = 0; j < JT; ++j) {
        int col = n0 + wn * (BN / 2) + j * 16 + l15;
        int hd = col - 2048;
        float bsv = bias[col];
        u16x4 pk;
        #pragma unroll
        for (int r = 0; r < 4; ++r) pk[r] = f2bf(acc[i][j][r] + bsv);
        *(u16x4*)&Vt[(size_t)(b_ * 1024 + hd) * Tt + t0] = pk;
      }
    }
  } else {
    const int ldc = (MODE == 1) ? 2048 : N;
    #pragma unroll
    for (int i = 0; i < 4; ++i) {
      int row = m0 + wm * 64 + i * 16 + lq * 4;
      #pragma unroll
      for (int j = 0; j < JT; ++j) {
        int col = n0 + wn * (BN / 2) + j * 16 + l15;
        float bsv = bias[col];
        #pragma unroll
        for (int r = 0; r < 4; ++r) {
          float v = acc[i][j][r] + bsv;
          if (MODE == 1) ((u16*)Cout)[(size_t)(row + r) * ldc + col] = f2bf(v);
          else           ((float*)Cout)[(size_t)(row + r) * ldc + col] = v;
        }
      }
    }
  }
}

// ============ fused causal flash attention — LDS-staged, swizzled, O^T ============
// Block = 256 thr = 4 waves, q-tile 64 (wave w: rows q0+w*16..+15), kv-tile 64.
// K and V^T staged global->LDS (coalesced gl2lds16, shared by all 4 waves) with
// XOR swizzle: slot s holds 16B chunk ((s&7)^((s>>3)&7)) of row s>>3, so
// fragment ds_reads are conflict-free. S^T = K*Q^T (A=K from LDS, B=Q regs).
// O^T = V^T*P: the same packp() vector is the PV B-fragment; V^T A-fragments
// come from LDS under the joint kv permutation. q-index lives in lane l15 for
// S^T, softmax state AND O^T -> zero cross-lane shuffles for alpha/epilogue.

__device__ __forceinline__ bf16x8 packp(const f32x4& a, const f32x4& b) {
  u16x8 u = { f2bf_fast(a[0]), f2bf_fast(a[1]), f2bf_fast(a[2]), f2bf_fast(a[3]),
              f2bf_fast(b[0]), f2bf_fast(b[1]), f2bf_fast(b[2]), f2bf_fast(b[3]) };
  return __builtin_bit_cast(bf16x8, u);
}
__device__ __forceinline__ bf16x8 qscale(const u16* p) {
  u16x8 q = *(const u16x8*)p;
  u16x8 s;
  #pragma unroll
  for (int j = 0; j < 8; ++j) s[j] = f2bf(bf2f(q[j]) * SCALE2);
  return __builtin_bit_cast(bf16x8, s);
}

__global__ __launch_bounds__(256, 4)
void attn_fused(const u16* __restrict__ qk, const u16* __restrict__ vt,
                u16* __restrict__ y) {
  __shared__ u16 Ks[64 * 64];    // swizzled [kv-row][d]
  __shared__ u16 Vts[64 * 64];   // swizzled [d-row][kv]
  const int tid = threadIdx.x;
  const int ln = tid & 63, w = tid >> 6;
  const int l15 = ln & 15, lq = ln >> 4;
  const int swz = l15 & 7;
  const int bx = blockIdx.x;
  const int bh = bx & 31;
  const int h  = bh & 15, b = bh >> 4;
  // balanced heavy/light rounds: each CU's 4 resident blocks sum to ~62 iters
  const int rr_ = bx >> 8, g = (bx >> 5) & 7;
  const int qt = (rr_ == 0) ? 31 - g : (rr_ == 1) ? 16 + g : (rr_ == 2) ? 15 - g : g;
  const int q0 = qt * 64;
  const int q0w = q0 + w * 16;

  const u16* qbase = qk + (size_t)(b * Tt) * 2048 + h * HD;
  const u16* kbase = qk + (size_t)(b * Tt) * 2048 + 1024 + h * HD;
  const u16* vbase = vt + (size_t)(b * 1024 + h * HD) * Tt;

  // staging: thread handles slots s0=tid, s1=256+tid; row=s>>3, swizzled chunk
  const int s0 = tid, s1 = 256 + tid;
  const int koff0 = (s0 >> 3) * 2048 + (((s0 & 7) ^ ((s0 >> 3) & 7)) * 8);
  const int koff1 = (s1 >> 3) * 2048 + (((s1 & 7) ^ ((s1 >> 3) & 7)) * 8);
  char* kd0 = (char*)Ks  + w * 1024;
  char* kd1 = (char*)Ks  + 4096 + w * 1024;
  char* vd0 = (char*)Vts + w * 1024;
  char* vd1 = (char*)Vts + 4096 + w * 1024;

  // Q B-fragments (n=q=l15, k=d), prescaled by 1/sqrt(d)*log2e
  const u16* qrA = qbase + (size_t)(q0w + l15) * 2048;
  bf16x8 qA0 = qscale(qrA + lq * 8), qA1 = qscale(qrA + 32 + lq * 8);

  f32x4 o[4];
  #pragma unroll
  for (int j = 0; j < 4; ++j) o[j] = (f32x4){0,0,0,0};
  float m = -__builtin_inff(), l = 0.f;
  const int qg = q0w + l15;

  const int nkv = qt + 1;
  for (int it = 0; it < nkv; ++it) {
    const int kk = it * 64;
    __syncthreads();   // previous iteration's LDS readers done
    {
      const u16* ksrc = kbase + (size_t)kk * 2048;
      const u16* vsrc = vbase + kk;
      gl2lds16(ksrc + koff0, kd0);
      gl2lds16(ksrc + koff1, kd1);
      gl2lds16(vsrc + koff0, vd0);
      gl2lds16(vsrc + koff1, vd1);
    }
    __syncthreads();   // staging complete (drains vmcnt)

    // S^T = K * Q^T
    f32x4 t[4];
    #pragma unroll
    for (int i = 0; i < 4; ++i) t[i] = (f32x4){0,0,0,0};
    #pragma unroll
    for (int i = 0; i < 4; ++i) {
      bf16x8 kf0 = ldb8(&Ks[(i * 16 + l15) * 64 + ((lq    ) ^ swz) * 8]);
      bf16x8 kf1 = ldb8(&Ks[(i * 16 + l15) * 64 + ((lq + 4) ^ swz) * 8]);
      t[i] = __builtin_amdgcn_mfma_f32_16x16x32_bf16(kf0, qA0, t[i], 0, 0, 0);
      t[i] = __builtin_amdgcn_mfma_f32_16x16x32_bf16(kf1, qA1, t[i], 0, 0, 0);
    }

    // online softmax over kv (log2 domain); state per q = per lane (l15)
    const bool lastI = (it == nkv - 1);
    if (lastI) {
      #pragma unroll
      for (int i = 0; i < 4; ++i)
        #pragma unroll
        for (int r = 0; r < 4; ++r) {
          int kv = kk + i * 16 + lq * 4 + r;
          if (kv > qg) t[i][r] = -__builtin_inff();
        }
    }
    float mx = t[0][0];
    #pragma unroll
    for (int i = 0; i < 4; ++i)
      #pragma unroll
      for (int r = 0; r < 4; ++r) mx = fmaxf(mx, t[i][r]);
    mx = fmaxf(mx, __shfl_xor(mx, 16));
    mx = fmaxf(mx, __shfl_xor(mx, 32));
    float mn = fmaxf(m, mx);
    float al = __builtin_amdgcn_exp2f(m - mn);
    float ps = 0.f;
    #pragma unroll
    for (int i = 0; i < 4; ++i)
      #pragma unroll
      for (int r = 0; r < 4; ++r) {
        float p = __builtin_amdgcn_exp2f(t[i][r] - mn);
        t[i][r] = p;
        ps += p;
      }
    ps += __shfl_xor(ps, 16);
    ps += __shfl_xor(ps, 32);
    l = l * al + ps;
    m = mn;
    #pragma unroll
    for (int jd = 0; jd < 4; ++jd)
      #pragma unroll
      for (int r = 0; r < 4; ++r) o[jd][r] *= al;   // per-lane alpha, no shuffle

    // O^T += V^T * P  (A = V^T frags from LDS, B = packp vectors)
    bf16x8 p0 = packp(t[0], t[1]), p1 = packp(t[2], t[3]);
    #pragma unroll
    for (int mf = 0; mf < 2; ++mf) {
      bf16x8 pb = mf ? p1 : p0;
      #pragma unroll
      for (int jd = 0; jd < 4; ++jd) {
        int d = jd * 16 + l15;
        int plo = ((mf * 4     + (lq >> 1)) ^ swz);
        int phi = ((mf * 4 + 2 + (lq >> 1)) ^ swz);
        u16x4 a = *(const u16x4*)&Vts[d * 64 + plo * 8 + (lq & 1) * 4];
        u16x4 c = *(const u16x4*)&Vts[d * 64 + phi * 8 + (lq & 1) * 4];
        u16x8 u = { a[0], a[1], a[2], a[3], c[0], c[1], c[2], c[3] };
        o[jd] = __builtin_amdgcn_mfma_f32_16x16x32_bf16(
                    __builtin_bit_cast(bf16x8, u), pb, o[jd], 0, 0, 0);
      }
    }
  }

  // epilogue: per-lane normalize, store O^T[d][q] -> y[q][d] as u16x4 runs
  float inv = 1.f / l;
  const size_t ybase = (size_t)(b * Tt + q0w + l15) * Cc + h * HD;
  #pragma unroll
  for (int jd = 0; jd < 4; ++jd) {
    u16x4 pk;
    #pragma unroll
    for (int r = 0; r < 4; ++r) pk[r] = f2bf(o[jd][r] * inv);
    *(u16x4*)&y[ybase + jd * 16 + lq * 4] = pk;
  }
}

extern "C" void kernel_launch(void* const* d_in, const int* in_sizes, int n_in,
                              void* d_out, int out_size, void* d_ws, size_t ws_size,
                              hipStream_t stream) {
  const float* x      = (const float*)d_in[0];
  const float* w_attn = (const float*)d_in[1];
  const float* b_attn = (const float*)d_in[2];
  const float* w_proj = (const float*)d_in[3];
  const float* b_proj = (const float*)d_in[4];
  float* out = (float*)d_out;

  char* ws = (char*)d_ws;
  u16* xb  = (u16*)(ws + 0);          // 4096x1024 bf16   (8 MB)
  u16* wat = (u16*)(ws + 8388608);    // 3072x1024 bf16   (6 MB)   w_attn^T
  u16* wpt = (u16*)(ws + 14680064);   // 1024x1024 bf16   (2 MB)   w_proj^T
  u16* qkb = (u16*)(ws + 16777216);   // 4096x2048 bf16   (16 MB)  Q,K
  u16* vtb = (u16*)(ws + 33554432);   // 2048x2048 bf16   (8 MB)   V^T per (b,h)
  u16* yb  = (u16*)(ws + 41943040);   // 4096x1024 bf16   (8 MB)

  cvt_x_kernel<<<4096, 256, 0, stream>>>(x, xb, 1048576);
  transpose_cvt<<<dim3(48, 16), 256, 0, stream>>>(w_attn, wat, 1024, 3072);
  transpose_cvt<<<dim3(16, 16), 256, 0, stream>>>(w_proj, wpt, 1024, 1024);
  gemm_bt<1, 128><<<dim3(24, 32), 256, 0, stream>>>(xb, wat, b_attn, (void*)qkb, vtb, 4096, 3072, 1024);
  attn_fused<<<1024, 256, 0, stream>>>(qkb, vtb, yb);
  gemm_bt<0, 64><<<dim3(16, 32), 256, 0, stream>>>(yb, wpt, b_proj, (void*)out, nullptr, 4096, 1024, 1024);
}

// Round 9
// 186.246 us; speedup vs baseline: 1.8888x; 1.0570x over previous
//
#include <hip/hip_runtime.h>
#include <stdint.h>

#define Bb 2
#define Tt 2048
#define Cc 1024
#define Hh 16
#define HD 64
#define C3 3072

typedef __bf16 bf16x8 __attribute__((ext_vector_type(8)));
typedef float  f32x4  __attribute__((ext_vector_type(4)));
typedef unsigned short u16;
typedef u16 u16x8 __attribute__((ext_vector_type(8)));
typedef u16 u16x4 __attribute__((ext_vector_type(4)));

#define SCALE2 0.18033688f  /* 1/sqrt(64) * log2(e) */

__device__ __forceinline__ u16 f2bf(float f) {
  union { float f; unsigned u; } v; v.f = f;
  return (u16)((v.u + 0x7fffu + ((v.u >> 16) & 1u)) >> 16);  // RNE
}
__device__ __forceinline__ u16 f2bf_fast(float f) {
  union { float f; unsigned u; } v; v.f = f;
  return (u16)((v.u + 0x8000u) >> 16);  // round-half-up, 2 instr
}
__device__ __forceinline__ float bf2f(u16 a) {
  union { unsigned u; float f; } v; v.u = ((unsigned)a) << 16; return v.f;
}

// async global->LDS, 16B per lane. LDS dest = wave-uniform base + lane*16.
__device__ __forceinline__ void gl2lds16(const void* g, void* s) {
  __builtin_amdgcn_global_load_lds(
      (__attribute__((address_space(1))) void*)(g),
      (__attribute__((address_space(3))) void*)(s), 16, 0, 0);
}

__device__ __forceinline__ bf16x8 ldb8(const u16* p) {
  return __builtin_bit_cast(bf16x8, *(const u16x8*)p);
}

// ---------------- merged prep: cvt_x + w_attn^T + w_proj^T ----------------
__global__ __launch_bounds__(256)
void prep_kernel(const float* __restrict__ x, const float* __restrict__ w_attn,
                 const float* __restrict__ w_proj, u16* __restrict__ xb,
                 u16* __restrict__ wat, u16* __restrict__ wpt) {
  __shared__ u16 tile[64][65];
  const int blk = blockIdx.x;
  const int tid = threadIdx.x;
  if (blk < 4096) {
    int i = blk * 256 + tid;
    float4 v = ((const float4*)x)[i];
    u16x4 o = { f2bf(v.x), f2bf(v.y), f2bf(v.z), f2bf(v.w) };
    ((u16x4*)xb)[i] = o;
    return;
  }
  const float* in; u16* out; int R, C, c0, r0;
  if (blk < 4096 + 768) {
    int t = blk - 4096;
    in = w_attn; out = wat; R = 1024; C = 3072;
    c0 = (t % 48) * 64; r0 = (t / 48) * 64;
  } else {
    int t = blk - 4864;
    in = w_proj; out = wpt; R = 1024; C = 1024;
    c0 = (t & 15) * 64; r0 = (t >> 4) * 64;
  }
  int xx = tid & 63, yy = tid >> 6;
  #pragma unroll
  for (int rr = yy; rr < 64; rr += 4)
    tile[rr][xx] = f2bf(in[(size_t)(r0 + rr) * C + c0 + xx]);
  __syncthreads();
  #pragma unroll
  for (int rr = yy; rr < 64; rr += 4)
    out[(size_t)(c0 + rr) * R + r0 + xx] = tile[xx][rr];
}

// ---------------- bf16 GEMM: C[M][N] = A[M][K] * Bt[N][K]^T + bias ----------------
// 128xBN block tile, BK=64, 4 waves (2x2). XOR-swizzled LDS (chunk ^= row&7).
// MODE 0: fp32 out, ldc=N.   MODE 1 (BN=128): bf16 out ldc=2048 for Q,K;
//   V cols (>=2048) written transposed AND kv-permuted into Vt[b][h][d][pos(t)]
//   (pos = within-64 permutation matching the attention PV A-fragment layout).
template <int MODE, int BN>
__global__ __launch_bounds__(256)
void gemm_bt(const u16* __restrict__ A, const u16* __restrict__ Bt,
             const float* __restrict__ bias, void* __restrict__ Cout,
             u16* __restrict__ Vt, int M, int N, int K) {
  __shared__ u16 As[128 * 64];
  __shared__ u16 Bs[BN * 64];
  constexpr int JT = BN / 32;          // j-tiles per wave
  const int tid = threadIdx.x;
  const int ln  = tid & 63;
  const int w   = tid >> 6;
  const int wm  = w >> 1, wn = w & 1;
  const int l15 = ln & 15, lq = ln >> 4;
  const int swz = l15 & 7;
  const int m0 = blockIdx.y * 128, n0 = blockIdx.x * BN;

  f32x4 acc[4][JT];
  #pragma unroll
  for (int i = 0; i < 4; ++i)
    #pragma unroll
    for (int j = 0; j < JT; ++j)
      acc[i][j] = (f32x4){0.f, 0.f, 0.f, 0.f};

  for (int k0 = 0; k0 < K; k0 += 64) {
    #pragma unroll
    for (int i = 0; i < 4; ++i) {       // A: 128 rows x 8 chunks = 1024 slots
      int s = i * 256 + tid;
      int row = s >> 3, cg = s & 7;
      gl2lds16(A + (size_t)(m0 + row) * K + k0 + ((cg ^ (row & 7)) * 8),
               (char*)As + (size_t)(i * 256 + w * 64) * 16);
    }
    #pragma unroll
    for (int i = 0; i < BN / 32; ++i) { // B: BN rows x 8 chunks
      int s = i * 256 + tid;
      int row = s >> 3, cg = s & 7;
      gl2lds16(Bt + (size_t)(n0 + row) * K + k0 + ((cg ^ (row & 7)) * 8),
               (char*)Bs + (size_t)(i * 256 + w * 64) * 16);
    }
    __syncthreads();
    #pragma unroll
    for (int ho = 0; ho < 2; ++ho) {    // two K=32 halves per staging phase
      bf16x8 af[4], bfr[JT];
      #pragma unroll
      for (int i = 0; i < 4; ++i)
        af[i] = ldb8(&As[(wm * 64 + i * 16 + l15) * 64 + ((ho * 4 + lq) ^ swz) * 8]);
      #pragma unroll
      for (int j = 0; j < JT; ++j)
        bfr[j] = ldb8(&Bs[(wn * (BN / 2) + j * 16 + l15) * 64 + ((ho * 4 + lq) ^ swz) * 8]);
      #pragma unroll
      for (int i = 0; i < 4; ++i)
        #pragma unroll
        for (int j = 0; j < JT; ++j)
          acc[i][j] = __builtin_amdgcn_mfma_f32_16x16x32_bf16(af[i], bfr[j], acc[i][j], 0, 0, 0);
    }
    __syncthreads();
  }

  if (MODE == 1 && n0 >= 2048) {
    // V block: transposed + kv-permuted into Vt[(b*16+h)*64+d][blk64 + pos]
    #pragma unroll
    for (int i = 0; i < 4; ++i) {
      int rowb = m0 + wm * 64 + i * 16 + lq * 4;   // 4 consecutive t
      int b_ = rowb >> 11, t0 = rowb & 2047;
      int tl = t0 & 63;
      int c = tl >> 4, ll = (tl >> 2) & 3;
      int pos0 = (c >> 1) * 32 + ll * 8 + (c & 1) * 4;
      size_t tdst = (size_t)(t0 & ~63) + pos0;
      #pragma unroll
      for (int j = 0; j < JT; ++j) {
        int col = n0 + wn * (BN / 2) + j * 16 + l15;
        int hd = col - 2048;
        float bsv = bias[col];
        u16x4 pk;
        #pragma unroll
        for (int r = 0; r < 4; ++r) pk[r] = f2bf(acc[i][j][r] + bsv);
        *(u16x4*)&Vt[(size_t)(b_ * 1024 + hd) * Tt + tdst] = pk;
      }
    }
  } else {
    const int ldc = (MODE == 1) ? 2048 : N;
    #pragma unroll
    for (int i = 0; i < 4; ++i) {
      int row = m0 + wm * 64 + i * 16 + lq * 4;
      #pragma unroll
      for (int j = 0; j < JT; ++j) {
        int col = n0 + wn * (BN / 2) + j * 16 + l15;
        float bsv = bias[col];
        #pragma unroll
        for (int r = 0; r < 4; ++r) {
          float v = acc[i][j][r] + bsv;
          if (MODE == 1) ((u16*)Cout)[(size_t)(row + r) * ldc + col] = f2bf(v);
          else           ((float*)Cout)[(size_t)(row + r) * ldc + col] = v;
        }
      }
    }
  }
}

// ============ fused causal flash attention — double-buffered LDS, O^T ============
// Block = 256 thr = 4 waves, q-tile 64, kv-tile 64. K and permuted-V^T staged
// global->LDS with XOR swizzle (conflict-free b128 fragment reads). DOUBLE
// BUFFERED: one barrier per iter; prefetch for tile it+1 issued right after
// the barrier -> its vmcnt drain happens a full iteration later (latency
// hidden). V^T is pre-permuted by gemm1 so PV A-fragments are single b128s.

__device__ __forceinline__ bf16x8 packp(const f32x4& a, const f32x4& b) {
  u16x8 u = { f2bf_fast(a[0]), f2bf_fast(a[1]), f2bf_fast(a[2]), f2bf_fast(a[3]),
              f2bf_fast(b[0]), f2bf_fast(b[1]), f2bf_fast(b[2]), f2bf_fast(b[3]) };
  return __builtin_bit_cast(bf16x8, u);
}
__device__ __forceinline__ bf16x8 qscale(const u16* p) {
  u16x8 q = *(const u16x8*)p;
  u16x8 s;
  #pragma unroll
  for (int j = 0; j < 8; ++j) s[j] = f2bf(bf2f(q[j]) * SCALE2);
  return __builtin_bit_cast(bf16x8, s);
}

__global__ __launch_bounds__(256, 4)
void attn_fused(const u16* __restrict__ qk, const u16* __restrict__ vt,
                u16* __restrict__ y) {
  __shared__ u16 Ks[2][64 * 64];    // swizzled [kv-row][d], double-buffered
  __shared__ u16 Vts[2][64 * 64];   // swizzled [d-row][kv-permuted]
  const int tid = threadIdx.x;
  const int ln = tid & 63, w = tid >> 6;
  const int l15 = ln & 15, lq = ln >> 4;
  const int swz = l15 & 7;
  const int bx = blockIdx.x;
  const int bh = bx & 31;
  const int h  = bh & 15, b = bh >> 4;
  // balanced heavy/light rounds: each CU's 4 resident blocks sum to ~62 iters
  const int rr_ = bx >> 8, g = (bx >> 5) & 7;
  const int qt = (rr_ == 0) ? 31 - g : (rr_ == 1) ? 16 + g : (rr_ == 2) ? 15 - g : g;
  const int q0 = qt * 64;
  const int q0w = q0 + w * 16;

  const u16* qbase = qk + (size_t)(b * Tt) * 2048 + h * HD;
  const u16* kbase = qk + (size_t)(b * Tt) * 2048 + 1024 + h * HD;
  const u16* vbase = vt + (size_t)(b * 1024 + h * HD) * Tt;

  // staging: thread handles slots s0=tid, s1=256+tid; row=s>>3, swizzled chunk
  const int s0 = tid, s1 = 256 + tid;
  const int koff0 = (s0 >> 3) * 2048 + (((s0 & 7) ^ ((s0 >> 3) & 7)) * 8);
  const int koff1 = (s1 >> 3) * 2048 + (((s1 & 7) ^ ((s1 >> 3) & 7)) * 8);

  // Q B-fragments (n=q=l15, k=d), prescaled by 1/sqrt(d)*log2e
  const u16* qrA = qbase + (size_t)(q0w + l15) * 2048;
  bf16x8 qA0 = qscale(qrA + lq * 8), qA1 = qscale(qrA + 32 + lq * 8);

  f32x4 o[4];
  #pragma unroll
  for (int j = 0; j < 4; ++j) o[j] = (f32x4){0,0,0,0};
  float m = -__builtin_inff(), l = 0.f;
  const int qg = q0w + l15;

  const int nkv = qt + 1;

  // prologue: stage tile 0 into buffer 0
  {
    const u16* ksrc = kbase;
    const u16* vsrc = vbase;
    gl2lds16(ksrc + koff0, (char*)Ks[0] + w * 1024);
    gl2lds16(ksrc + koff1, (char*)Ks[0] + 4096 + w * 1024);
    gl2lds16(vsrc + koff0, (char*)Vts[0] + w * 1024);
    gl2lds16(vsrc + koff1, (char*)Vts[0] + 4096 + w * 1024);
  }

  for (int it = 0; it < nkv; ++it) {
    const int kk = it * 64;
    const int p = it & 1;
    __syncthreads();   // tile `it` staged (vmcnt drained); buf p^1 readers done
    if (it + 1 < nkv) {
      const u16* ksrc = kbase + (size_t)(kk + 64) * 2048;
      const u16* vsrc = vbase + kk + 64;
      gl2lds16(ksrc + koff0, (char*)Ks[p ^ 1] + w * 1024);
      gl2lds16(ksrc + koff1, (char*)Ks[p ^ 1] + 4096 + w * 1024);
      gl2lds16(vsrc + koff0, (char*)Vts[p ^ 1] + w * 1024);
      gl2lds16(vsrc + koff1, (char*)Vts[p ^ 1] + 4096 + w * 1024);
    }
    const u16* KsB  = Ks[p];
    const u16* VtsB = Vts[p];

    // S^T = K * Q^T
    f32x4 t[4];
    #pragma unroll
    for (int i = 0; i < 4; ++i) t[i] = (f32x4){0,0,0,0};
    #pragma unroll
    for (int i = 0; i < 4; ++i) {
      bf16x8 kf0 = ldb8(&KsB[(i * 16 + l15) * 64 + ((lq    ) ^ swz) * 8]);
      bf16x8 kf1 = ldb8(&KsB[(i * 16 + l15) * 64 + ((lq + 4) ^ swz) * 8]);
      t[i] = __builtin_amdgcn_mfma_f32_16x16x32_bf16(kf0, qA0, t[i], 0, 0, 0);
      t[i] = __builtin_amdgcn_mfma_f32_16x16x32_bf16(kf1, qA1, t[i], 0, 0, 0);
    }

    // online softmax over kv (log2 domain); state per q = per lane (l15)
    const bool lastI = (it == nkv - 1);
    if (lastI) {
      #pragma unroll
      for (int i = 0; i < 4; ++i)
        #pragma unroll
        for (int r = 0; r < 4; ++r) {
          int kv = kk + i * 16 + lq * 4 + r;
          if (kv > qg) t[i][r] = -__builtin_inff();
        }
    }
    float mx = t[0][0];
    #pragma unroll
    for (int i = 0; i < 4; ++i)
      #pragma unroll
      for (int r = 0; r < 4; ++r) mx = fmaxf(mx, t[i][r]);
    mx = fmaxf(mx, __shfl_xor(mx, 16));
    mx = fmaxf(mx, __shfl_xor(mx, 32));
    float mn = fmaxf(m, mx);
    float al = __builtin_amdgcn_exp2f(m - mn);
    float ps = 0.f;
    #pragma unroll
    for (int i = 0; i < 4; ++i)
      #pragma unroll
      for (int r = 0; r < 4; ++r) {
        float pp = __builtin_amdgcn_exp2f(t[i][r] - mn);
        t[i][r] = pp;
        ps += pp;
      }
    ps += __shfl_xor(ps, 16);
    ps += __shfl_xor(ps, 32);
    l = l * al + ps;
    m = mn;
    #pragma unroll
    for (int jd = 0; jd < 4; ++jd)
      #pragma unroll
      for (int r = 0; r < 4; ++r) o[jd][r] *= al;   // per-lane alpha, no shuffle

    // O^T += V^T * P  (A = permuted V^T b128 frags from LDS, B = packp vectors)
    bf16x8 p0 = packp(t[0], t[1]), p1 = packp(t[2], t[3]);
    #pragma unroll
    for (int mf = 0; mf < 2; ++mf) {
      bf16x8 pb = mf ? p1 : p0;
      #pragma unroll
      for (int jd = 0; jd < 4; ++jd) {
        int d = jd * 16 + l15;
        bf16x8 vf = ldb8(&VtsB[d * 64 + ((mf * 4 + lq) ^ swz) * 8]);
        o[jd] = __builtin_amdgcn_mfma_f32_16x16x32_bf16(vf, pb, o[jd], 0, 0, 0);
      }
    }
  }

  // epilogue: per-lane normalize, store O^T[d][q] -> y[q][d] as u16x4 runs
  float inv = 1.f / l;
  const size_t ybase = (size_t)(b * Tt + q0w + l15) * Cc + h * HD;
  #pragma unroll
  for (int jd = 0; jd < 4; ++jd) {
    u16x4 pk;
    #pragma unroll
    for (int r = 0; r < 4; ++r) pk[r] = f2bf(o[jd][r] * inv);
    *(u16x4*)&y[ybase + jd * 16 + lq * 4] = pk;
  }
}

extern "C" void kernel_launch(void* const* d_in, const int* in_sizes, int n_in,
                              void* d_out, int out_size, void* d_ws, size_t ws_size,
                              hipStream_t stream) {
  const float* x      = (const float*)d_in[0];
  const float* w_attn = (const float*)d_in[1];
  const float* b_attn = (const float*)d_in[2];
  const float* w_proj = (const float*)d_in[3];
  const float* b_proj = (const float*)d_in[4];
  float* out = (float*)d_out;

  char* ws = (char*)d_ws;
  u16* xb  = (u16*)(ws + 0);          // 4096x1024 bf16   (8 MB)
  u16* wat = (u16*)(ws + 8388608);    // 3072x1024 bf16   (6 MB)   w_attn^T
  u16* wpt = (u16*)(ws + 14680064);   // 1024x1024 bf16   (2 MB)   w_proj^T
  u16* qkb = (u16*)(ws + 16777216);   // 4096x2048 bf16   (16 MB)  Q,K
  u16* vtb = (u16*)(ws + 33554432);   // 2048x2048 bf16   (8 MB)   V^T (permuted)
  u16* yb  = (u16*)(ws + 41943040);   // 4096x1024 bf16   (8 MB)

  prep_kernel<<<5120, 256, 0, stream>>>(x, w_attn, w_proj, xb, wat, wpt);
  gemm_bt<1, 128><<<dim3(24, 32), 256, 0, stream>>>(xb, wat, b_attn, (void*)qkb, vtb, 4096, 3072, 1024);
  attn_fused<<<1024, 256, 0, stream>>>(qkb, vtb, yb);
  gemm_bt<0, 64><<<dim3(16, 32), 256, 0, stream>>>(yb, wpt, b_proj, (void*)out, nullptr, 4096, 1024, 1024);
}

// Round 10
// 178.656 us; speedup vs baseline: 1.9690x; 1.0425x over previous
//
#include <hip/hip_runtime.h>
#include <stdint.h>

#define Bb 2
#define Tt 2048
#define Cc 1024
#define Hh 16
#define HD 64
#define C3 3072

typedef __bf16 bf16x8 __attribute__((ext_vector_type(8)));
typedef float  f32x4  __attribute__((ext_vector_type(4)));
typedef unsigned short u16;
typedef u16 u16x8 __attribute__((ext_vector_type(8)));
typedef u16 u16x4 __attribute__((ext_vector_type(4)));

#define SCALE2 0.18033688f  /* 1/sqrt(64) * log2(e) */

__device__ __forceinline__ u16 f2bf(float f) {
  union { float f; unsigned u; } v; v.f = f;
  return (u16)((v.u + 0x7fffu + ((v.u >> 16) & 1u)) >> 16);  // RNE
}
__device__ __forceinline__ u16 f2bf_fast(float f) {
  union { float f; unsigned u; } v; v.f = f;
  return (u16)((v.u + 0x8000u) >> 16);  // round-half-up, 2 instr
}
__device__ __forceinline__ float bf2f(u16 a) {
  union { unsigned u; float f; } v; v.u = ((unsigned)a) << 16; return v.f;
}

// async global->LDS, 16B per lane. LDS dest = wave-uniform base + lane*16.
__device__ __forceinline__ void gl2lds16(const void* g, void* s) {
  __builtin_amdgcn_global_load_lds(
      (__attribute__((address_space(1))) void*)(g),
      (__attribute__((address_space(3))) void*)(s), 16, 0, 0);
}

__device__ __forceinline__ bf16x8 ldb8(const u16* p) {
  return __builtin_bit_cast(bf16x8, *(const u16x8*)p);
}

// ---------------- merged prep: cvt_x + w_attn^T + w_proj^T ----------------
__global__ __launch_bounds__(256)
void prep_kernel(const float* __restrict__ x, const float* __restrict__ w_attn,
                 const float* __restrict__ w_proj, u16* __restrict__ xb,
                 u16* __restrict__ wat, u16* __restrict__ wpt) {
  __shared__ u16 tile[64][65];
  const int blk = blockIdx.x;
  const int tid = threadIdx.x;
  if (blk < 4096) {
    int i = blk * 256 + tid;
    float4 v = ((const float4*)x)[i];
    u16x4 o = { f2bf(v.x), f2bf(v.y), f2bf(v.z), f2bf(v.w) };
    ((u16x4*)xb)[i] = o;
    return;
  }
  const float* in; u16* out; int R, C, c0, r0;
  if (blk < 4096 + 768) {
    int t = blk - 4096;
    in = w_attn; out = wat; R = 1024; C = 3072;
    c0 = (t % 48) * 64; r0 = (t / 48) * 64;
  } else {
    int t = blk - 4864;
    in = w_proj; out = wpt; R = 1024; C = 1024;
    c0 = (t & 15) * 64; r0 = (t >> 4) * 64;
  }
  int xx = tid & 63, yy = tid >> 6;
  #pragma unroll
  for (int rr = yy; rr < 64; rr += 4)
    tile[rr][xx] = f2bf(in[(size_t)(r0 + rr) * C + c0 + xx]);
  __syncthreads();
  #pragma unroll
  for (int rr = yy; rr < 64; rr += 4)
    out[(size_t)(c0 + rr) * R + r0 + xx] = tile[xx][rr];
}

// ---------------- bf16 GEMM: C[M][N] = A[M][K] * Bt[N][K]^T + bias ----------------
// 128xBN tile, BK=32, DOUBLE-BUFFERED LDS: one barrier/iter, prefetch for iter
// it+1 issued right after the barrier -> each vmcnt drain is covered by a full
// iteration of compute. 4-chunk XOR swizzle: slot s holds global chunk
// (s&3)^((s>>3)&3); reader chunk = lq ^ ((l15>>1)&3) -> bank-granule pattern
// {0,4,1,5,2,6,3,7} per 8-lane phase, conflict-free.
// MODE 0: fp32 out, ldc=N.   MODE 1 (BN=128): bf16 out ldc=2048 for Q,K;
//   V cols (>=2048) written transposed AND kv-permuted into Vt[b][h][d][pos(t)].
template <int MODE, int BN>
__global__ __launch_bounds__(256, 4)
void gemm_bt(const u16* __restrict__ A, const u16* __restrict__ Bt,
             const float* __restrict__ bias, void* __restrict__ Cout,
             u16* __restrict__ Vt, int M, int N, int K) {
  __shared__ u16 As[2][128 * 32];
  __shared__ u16 Bs[2][BN * 32];
  constexpr int JT = BN / 32;          // j-tiles per wave
  const int tid = threadIdx.x;
  const int ln  = tid & 63;
  const int w   = tid >> 6;
  const int wm  = w >> 1, wn = w & 1;
  const int l15 = ln & 15, lq = ln >> 4;
  const int swz2 = (l15 >> 1) & 3;
  const int m0 = blockIdx.y * 128, n0 = blockIdx.x * BN;

  // staging source offsets (row-swizzled 4-chunk)
  int aoff[2], boff[BN / 128 + 1];
  #pragma unroll
  for (int i = 0; i < 2; ++i) {
    int s = i * 256 + tid;                 // A: 512 slots
    int row = s >> 2, cg = (s & 3) ^ ((s >> 3) & 3);
    aoff[i] = (m0 + row) * K + cg * 8;
  }
  #pragma unroll
  for (int i = 0; i < BN / 128 + 1; ++i) { // B: BN*4 slots (512 or 256)
    int s = i * 256 + tid;
    int row = s >> 2, cg = (s & 3) ^ ((s >> 3) & 3);
    boff[i] = (n0 + row) * K + cg * 8;
  }

  f32x4 acc[4][JT];
  #pragma unroll
  for (int i = 0; i < 4; ++i)
    #pragma unroll
    for (int j = 0; j < JT; ++j)
      acc[i][j] = (f32x4){0.f, 0.f, 0.f, 0.f};

  const int NK = K >> 5;
  // prologue: stage k-tile 0 into buffer 0
  #pragma unroll
  for (int i = 0; i < 2; ++i)
    gl2lds16(A + aoff[i], (char*)As[0] + (size_t)(i * 256 + w * 64) * 16);
  #pragma unroll
  for (int i = 0; i < BN / 128 + 1; ++i)
    gl2lds16(Bt + boff[i], (char*)Bs[0] + (size_t)(i * 256 + w * 64) * 16);

  for (int it = 0; it < NK; ++it) {
    const int p = it & 1;
    __syncthreads();   // tile `it` landed (vmcnt drained); buf p^1 readers done
    if (it + 1 < NK) {
      const int k0 = (it + 1) * 32;
      #pragma unroll
      for (int i = 0; i < 2; ++i)
        gl2lds16(A + aoff[i] + k0, (char*)As[p ^ 1] + (size_t)(i * 256 + w * 64) * 16);
      #pragma unroll
      for (int i = 0; i < BN / 128 + 1; ++i)
        gl2lds16(Bt + boff[i] + k0, (char*)Bs[p ^ 1] + (size_t)(i * 256 + w * 64) * 16);
    }
    const u16* AsB = As[p];
    const u16* BsB = Bs[p];
    bf16x8 af[4], bfr[JT];
    #pragma unroll
    for (int i = 0; i < 4; ++i)
      af[i] = ldb8(&AsB[(wm * 64 + i * 16 + l15) * 32 + ((lq ^ swz2) * 8)]);
    #pragma unroll
    for (int j = 0; j < JT; ++j)
      bfr[j] = ldb8(&BsB[(wn * (BN / 2) + j * 16 + l15) * 32 + ((lq ^ swz2) * 8)]);
    #pragma unroll
    for (int i = 0; i < 4; ++i)
      #pragma unroll
      for (int j = 0; j < JT; ++j)
        acc[i][j] = __builtin_amdgcn_mfma_f32_16x16x32_bf16(af[i], bfr[j], acc[i][j], 0, 0, 0);
  }

  if (MODE == 1 && n0 >= 2048) {
    // V block: transposed + kv-permuted into Vt[(b*16+h)*64+d][blk64 + pos]
    #pragma unroll
    for (int i = 0; i < 4; ++i) {
      int rowb = m0 + wm * 64 + i * 16 + lq * 4;   // 4 consecutive t
      int b_ = rowb >> 11, t0 = rowb & 2047;
      int tl = t0 & 63;
      int c = tl >> 4, ll = (tl >> 2) & 3;
      int pos0 = (c >> 1) * 32 + ll * 8 + (c & 1) * 4;
      size_t tdst = (size_t)(t0 & ~63) + pos0;
      #pragma unroll
      for (int j = 0; j < JT; ++j) {
        int col = n0 + wn * (BN / 2) + j * 16 + l15;
        int hd = col - 2048;
        float bsv = bias[col];
        u16x4 pk;
        #pragma unroll
        for (int r = 0; r < 4; ++r) pk[r] = f2bf(acc[i][j][r] + bsv);
        *(u16x4*)&Vt[(size_t)(b_ * 1024 + hd) * Tt + tdst] = pk;
      }
    }
  } else {
    const int ldc = (MODE == 1) ? 2048 : N;
    #pragma unroll
    for (int i = 0; i < 4; ++i) {
      int row = m0 + wm * 64 + i * 16 + lq * 4;
      #pragma unroll
      for (int j = 0; j < JT; ++j) {
        int col = n0 + wn * (BN / 2) + j * 16 + l15;
        float bsv = bias[col];
        #pragma unroll
        for (int r = 0; r < 4; ++r) {
          float v = acc[i][j][r] + bsv;
          if (MODE == 1) ((u16*)Cout)[(size_t)(row + r) * ldc + col] = f2bf(v);
          else           ((float*)Cout)[(size_t)(row + r) * ldc + col] = v;
        }
      }
    }
  }
}

// ============ fused causal flash attention — double-buffered LDS, O^T ============
// Block = 256 thr = 4 waves, q-tile 64, kv-tile 64. K and permuted-V^T staged
// global->LDS with XOR swizzle (conflict-free b128 fragment reads). Double
// buffered: one barrier per iter; prefetch for tile it+1 issued right after
// the barrier. V^T is pre-permuted by gemm1 so PV A-fragments are single b128s.

__device__ __forceinline__ bf16x8 packp(const f32x4& a, const f32x4& b) {
  u16x8 u = { f2bf_fast(a[0]), f2bf_fast(a[1]), f2bf_fast(a[2]), f2bf_fast(a[3]),
              f2bf_fast(b[0]), f2bf_fast(b[1]), f2bf_fast(b[2]), f2bf_fast(b[3]) };
  return __builtin_bit_cast(bf16x8, u);
}
__device__ __forceinline__ bf16x8 qscale(const u16* p) {
  u16x8 q = *(const u16x8*)p;
  u16x8 s;
  #pragma unroll
  for (int j = 0; j < 8; ++j) s[j] = f2bf(bf2f(q[j]) * SCALE2);
  return __builtin_bit_cast(bf16x8, s);
}

__global__ __launch_bounds__(256, 4)
void attn_fused(const u16* __restrict__ qk, const u16* __restrict__ vt,
                u16* __restrict__ y) {
  __shared__ u16 Ks[2][64 * 64];    // swizzled [kv-row][d], double-buffered
  __shared__ u16 Vts[2][64 * 64];   // swizzled [d-row][kv-permuted]
  const int tid = threadIdx.x;
  const int ln = tid & 63, w = tid >> 6;
  const int l15 = ln & 15, lq = ln >> 4;
  const int swz = l15 & 7;
  const int bx = blockIdx.x;
  const int bh = bx & 31;
  const int h  = bh & 15, b = bh >> 4;
  // balanced heavy/light rounds: each CU's 4 resident blocks sum to ~62 iters
  const int rr_ = bx >> 8, g = (bx >> 5) & 7;
  const int qt = (rr_ == 0) ? 31 - g : (rr_ == 1) ? 16 + g : (rr_ == 2) ? 15 - g : g;
  const int q0 = qt * 64;
  const int q0w = q0 + w * 16;

  const u16* qbase = qk + (size_t)(b * Tt) * 2048 + h * HD;
  const u16* kbase = qk + (size_t)(b * Tt) * 2048 + 1024 + h * HD;
  const u16* vbase = vt + (size_t)(b * 1024 + h * HD) * Tt;

  // staging: thread handles slots s0=tid, s1=256+tid; row=s>>3, swizzled chunk
  const int s0 = tid, s1 = 256 + tid;
  const int koff0 = (s0 >> 3) * 2048 + (((s0 & 7) ^ ((s0 >> 3) & 7)) * 8);
  const int koff1 = (s1 >> 3) * 2048 + (((s1 & 7) ^ ((s1 >> 3) & 7)) * 8);

  // Q B-fragments (n=q=l15, k=d), prescaled by 1/sqrt(d)*log2e
  const u16* qrA = qbase + (size_t)(q0w + l15) * 2048;
  bf16x8 qA0 = qscale(qrA + lq * 8), qA1 = qscale(qrA + 32 + lq * 8);

  f32x4 o[4];
  #pragma unroll
  for (int j = 0; j < 4; ++j) o[j] = (f32x4){0,0,0,0};
  float m = -__builtin_inff(), l = 0.f;
  const int qg = q0w + l15;

  const int nkv = qt + 1;

  // prologue: stage tile 0 into buffer 0
  {
    gl2lds16(kbase + koff0, (char*)Ks[0] + w * 1024);
    gl2lds16(kbase + koff1, (char*)Ks[0] + 4096 + w * 1024);
    gl2lds16(vbase + koff0, (char*)Vts[0] + w * 1024);
    gl2lds16(vbase + koff1, (char*)Vts[0] + 4096 + w * 1024);
  }

  for (int it = 0; it < nkv; ++it) {
    const int kk = it * 64;
    const int p = it & 1;
    __syncthreads();   // tile `it` staged (vmcnt drained); buf p^1 readers done
    if (it + 1 < nkv) {
      const u16* ksrc = kbase + (size_t)(kk + 64) * 2048;
      const u16* vsrc = vbase + kk + 64;
      gl2lds16(ksrc + koff0, (char*)Ks[p ^ 1] + w * 1024);
      gl2lds16(ksrc + koff1, (char*)Ks[p ^ 1] + 4096 + w * 1024);
      gl2lds16(vsrc + koff0, (char*)Vts[p ^ 1] + w * 1024);
      gl2lds16(vsrc + koff1, (char*)Vts[p ^ 1] + 4096 + w * 1024);
    }
    const u16* KsB  = Ks[p];
    const u16* VtsB = Vts[p];

    // S^T = K * Q^T
    f32x4 t[4];
    #pragma unroll
    for (int i = 0; i < 4; ++i) t[i] = (f32x4){0,0,0,0};
    #pragma unroll
    for (int i = 0; i < 4; ++i) {
      bf16x8 kf0 = ldb8(&KsB[(i * 16 + l15) * 64 + ((lq    ) ^ swz) * 8]);
      bf16x8 kf1 = ldb8(&KsB[(i * 16 + l15) * 64 + ((lq + 4) ^ swz) * 8]);
      t[i] = __builtin_amdgcn_mfma_f32_16x16x32_bf16(kf0, qA0, t[i], 0, 0, 0);
      t[i] = __builtin_amdgcn_mfma_f32_16x16x32_bf16(kf1, qA1, t[i], 0, 0, 0);
    }

    // online softmax over kv (log2 domain); state per q = per lane (l15)
    const bool lastI = (it == nkv - 1);
    if (lastI) {
      #pragma unroll
      for (int i = 0; i < 4; ++i)
        #pragma unroll
        for (int r = 0; r < 4; ++r) {
          int kv = kk + i * 16 + lq * 4 + r;
          if (kv > qg) t[i][r] = -__builtin_inff();
        }
    }
    float mx = t[0][0];
    #pragma unroll
    for (int i = 0; i < 4; ++i)
      #pragma unroll
      for (int r = 0; r < 4; ++r) mx = fmaxf(mx, t[i][r]);
    mx = fmaxf(mx, __shfl_xor(mx, 16));
    mx = fmaxf(mx, __shfl_xor(mx, 32));
    float mn = fmaxf(m, mx);
    float al = __builtin_amdgcn_exp2f(m - mn);
    float ps = 0.f;
    #pragma unroll
    for (int i = 0; i < 4; ++i)
      #pragma unroll
      for (int r = 0; r < 4; ++r) {
        float pp = __builtin_amdgcn_exp2f(t[i][r] - mn);
        t[i][r] = pp;
        ps += pp;
      }
    ps += __shfl_xor(ps, 16);
    ps += __shfl_xor(ps, 32);
    l = l * al + ps;
    m = mn;
    #pragma unroll
    for (int jd = 0; jd < 4; ++jd)
      #pragma unroll
      for (int r = 0; r < 4; ++r) o[jd][r] *= al;   // per-lane alpha, no shuffle

    // O^T += V^T * P  (A = permuted V^T b128 frags from LDS, B = packp vectors)
    bf16x8 p0 = packp(t[0], t[1]), p1 = packp(t[2], t[3]);
    #pragma unroll
    for (int mf = 0; mf < 2; ++mf) {
      bf16x8 pb = mf ? p1 : p0;
      #pragma unroll
      for (int jd = 0; jd < 4; ++jd) {
        int d = jd * 16 + l15;
        bf16x8 vf = ldb8(&VtsB[d * 64 + ((mf * 4 + lq) ^ swz) * 8]);
        o[jd] = __builtin_amdgcn_mfma_f32_16x16x32_bf16(vf, pb, o[jd], 0, 0, 0);
      }
    }
  }

  // epilogue: per-lane normalize, store O^T[d][q] -> y[q][d] as u16x4 runs
  float inv = 1.f / l;
  const size_t ybase = (size_t)(b * Tt + q0w + l15) * Cc + h * HD;
  #pragma unroll
  for (int jd = 0; jd < 4; ++jd) {
    u16x4 pk;
    #pragma unroll
    for (int r = 0; r < 4; ++r) pk[r] = f2bf(o[jd][r] * inv);
    *(u16x4*)&y[ybase + jd * 16 + lq * 4] = pk;
  }
}

extern "C" void kernel_launch(void* const* d_in, const int* in_sizes, int n_in,
                              void* d_out, int out_size, void* d_ws, size_t ws_size,
                              hipStream_t stream) {
  const float* x      = (const float*)d_in[0];
  const float* w_attn = (const float*)d_in[1];
  const float* b_attn = (const float*)d_in[2];
  const float* w_proj = (const float*)d_in[3];
  const float* b_proj = (const float*)d_in[4];
  float* out = (float*)d_out;

  char* ws = (char*)d_ws;
  u16* xb  = (u16*)(ws + 0);          // 4096x1024 bf16   (8 MB)
  u16* wat = (u16*)(ws + 8388608);    // 3072x1024 bf16   (6 MB)   w_attn^T
  u16* wpt = (u16*)(ws + 14680064);   // 1024x1024 bf16   (2 MB)   w_proj^T
  u16* qkb = (u16*)(ws + 16777216);   // 4096x2048 bf16   (16 MB)  Q,K
  u16* vtb = (u16*)(ws + 33554432);   // 2048x2048 bf16   (8 MB)   V^T (permuted)
  u16* yb  = (u16*)(ws + 41943040);   // 4096x1024 bf16   (8 MB)

  prep_kernel<<<5120, 256, 0, stream>>>(x, w_attn, w_proj, xb, wat, wpt);
  gemm_bt<1, 128><<<dim3(24, 32), 256, 0, stream>>>(xb, wat, b_attn, (void*)qkb, vtb, 4096, 3072, 1024);
  attn_fused<<<1024, 256, 0, stream>>>(qkb, vtb, yb);
  gemm_bt<0, 64><<<dim3(16, 32), 256, 0, stream>>>(yb, wpt, b_proj, (void*)out, nullptr, 4096, 1024, 1024);
}